// Round 14
// baseline (224.043 us; speedup 1.0000x reference)
//
#include <hip/hip_runtime.h>

// Problem constants (from reference)
#define N_NODES 100000
#define N_EDGES 1600000
#define N_REL   5
#define NCOARSE  196                         // ceil(N_NODES / 512) coarse buckets
#define CAP      16384                       // pe capacity per coarse bucket (avg 8163)

using bf16x8 = __attribute__((ext_vector_type(8))) short;
using f32x4  = __attribute__((ext_vector_type(4))) float;
using f32x2  = __attribute__((ext_vector_type(2))) float;
using i32x2  = __attribute__((ext_vector_type(2))) int;

__device__ __forceinline__ unsigned short f2bf(float f) {
    unsigned int u = __float_as_uint(f);
    u += 0x7fffu + ((u >> 16) & 1u);          // RNE
    return (unsigned short)(u >> 16);
}
__device__ __forceinline__ float bfu(unsigned short u) { return __uint_as_float((unsigned int)u << 16); }

// ---------------------------------------------------------------------------
// Pass 1: append edges into coarse (dst>>9) regions of pe.
// Record = (src | rel<<17 | dlow9<<20, ew).
// ---------------------------------------------------------------------------
__global__ __launch_bounds__(1024) void partition_append(
    const int* __restrict__ src, const int* __restrict__ dstv,
    const float* __restrict__ ew, const int* __restrict__ et,
    int* __restrict__ ccur, int2* __restrict__ pe) {
    __shared__ int lh[256];
    __shared__ int lb[256];
    int tid = threadIdx.x;
    if (tid < 256) lh[tid] = 0;
    __syncthreads();
    int base = blockIdx.x * 4096;
    int key[4], rank[4], meta[4];
    float w[4];
    #pragma unroll
    for (int i = 0; i < 4; ++i) {
        int e = base + i * 1024 + tid;
        key[i] = -1;
        if (e < N_EDGES) {
            int d = dstv[e];
            key[i] = d >> 9;
            meta[i] = src[e] | (et[e] << 17) | ((d & 511) << 20);
            w[i] = ew[e];
            rank[i] = atomicAdd(&lh[key[i]], 1);
        }
    }
    __syncthreads();
    if (tid < 256) {
        int c = lh[tid];
        lb[tid] = c ? atomicAdd(&ccur[tid], c) : 0;
    }
    __syncthreads();
    #pragma unroll
    for (int i = 0; i < 4; ++i)
        if (key[i] >= 0) {
            int pos = lb[key[i]] + rank[i];
            if (pos < CAP)
                pe[((size_t)key[i] << 14) + pos] = make_int2(meta[i], __float_as_int(w[i]));
        }
}

// Pass 2 (tiny): exclusive scan of 256 coarse counts -> global bases.
__global__ __launch_bounds__(256) void cscan(const int* __restrict__ ccur,
                                             int* __restrict__ cstart) {
    __shared__ int lds[256];
    int tid = threadIdx.x;
    int v = ccur[tid];
    lds[tid] = v;
    __syncthreads();
    for (int d = 1; d < 256; d <<= 1) {
        int t = (tid >= d) ? lds[tid - d] : 0;
        __syncthreads();
        lds[tid] += t;
        __syncthreads();
    }
    cstart[tid] = lds[tid] - v;
}

// ---------------------------------------------------------------------------
// Pass 3: one block per coarse bucket. Fine histogram, wave-shfl scan,
// per-node descriptors (nbase + packed relation boundaries), dense scatter.
// pe is dead after this kernel -> non-temporal loads (don't retain in L3).
// ---------------------------------------------------------------------------
__global__ __launch_bounds__(1024) void bucket_sort(
    const int* __restrict__ ccnt, const int* __restrict__ cstart,
    const int2* __restrict__ pe, int2* __restrict__ edges,
    int* __restrict__ nbase, int2* __restrict__ nbp) {
    int cb = blockIdx.x;
    int node0 = cb << 9;
    if (node0 >= N_NODES) return;
    int nNodes = N_NODES - node0; if (nNodes > 512) nNodes = 512;
    int nf = nNodes * N_REL;
    __shared__ int hist[2560];
    __shared__ int cur[2560];
    __shared__ int wtot[16];
    __shared__ int woff[16];
    int tid = threadIdx.x;
    int wid = tid >> 6, lane = tid & 63;
    int cnt = ccnt[cb]; if (cnt > CAP) cnt = CAP;
    int gbase = cstart[cb];
    const i32x2* my = reinterpret_cast<const i32x2*>(pe) + ((size_t)cb << 14);

    for (int i = tid; i < nf; i += 1024) hist[i] = 0;
    __syncthreads();
    for (int i = tid; i < cnt; i += 1024) {
        i32x2 r = __builtin_nontemporal_load(&my[i]);
        atomicAdd(&hist[((r.x >> 20) & 511) * N_REL + ((r.x >> 17) & 7)], 1);
    }
    __syncthreads();

    // exclusive scan over hist: 3 elems/thread, wave shfl-scan + 16 partials
    int t0 = tid * 3;
    int a0 = (t0 + 0 < nf) ? hist[t0 + 0] : 0;
    int a1 = (t0 + 1 < nf) ? hist[t0 + 1] : 0;
    int a2 = (t0 + 2 < nf) ? hist[t0 + 2] : 0;
    int s = a0 + a1 + a2;
    int incl = s;
    #pragma unroll
    for (int d = 1; d < 64; d <<= 1) {
        int t = __shfl_up(incl, d);
        if (lane >= d) incl += t;
    }
    if (lane == 63) wtot[wid] = incl;
    __syncthreads();
    if (wid == 0 && lane < 16) {
        int v = wtot[lane];
        int inc2 = v;
        #pragma unroll
        for (int d = 1; d < 16; d <<= 1) {
            int t = __shfl_up(inc2, d);
            if (lane >= d) inc2 += t;
        }
        woff[lane] = inc2 - v;
    }
    __syncthreads();
    int excl = incl - s + woff[wid];
    if (t0 + 0 < nf) cur[t0 + 0] = excl;
    excl += a0;
    if (t0 + 1 < nf) cur[t0 + 1] = excl;
    excl += a1;
    if (t0 + 2 < nf) cur[t0 + 2] = excl;
    __syncthreads();

    // per-node descriptors: base + packed boundaries (B1..B4) + true degree
    for (int i = tid; i < nNodes; i += 1024) {
        int b = i * N_REL;
        int c0 = cur[b];
        int B1 = cur[b + 1] - c0, B2 = cur[b + 2] - c0;
        int B3 = cur[b + 3] - c0, B4 = cur[b + 4] - c0;
        int deg = cur[b + 4] + hist[b + 4] - c0;
        nbase[node0 + i] = gbase + c0;
        nbp[node0 + i] = make_int2(B1 | (B2 << 8) | (B3 << 16) | (B4 << 24), deg);
    }
    __syncthreads();

    for (int i = tid; i < cnt; i += 1024) {
        i32x2 r = __builtin_nontemporal_load(&my[i]);
        int fb = ((r.x >> 20) & 511) * N_REL + ((r.x >> 17) & 7);
        int pos = gbase + atomicAdd(&cur[fb], 1);
        float wf = __uint_as_float((unsigned)r.y) / (float)hist[fb];   // fold 1/deg
        edges[pos] = make_int2(r.x & 0xFFFFF, __float_as_int(wf)); // src|rel<<17
    }
}

// ---------------------------------------------------------------------------
// Feature conversion: one read of x (non-temporal — never re-read) ->
// xh (bf16, cached) + xq (fp8 e4m3, cached — re-read heavily by gather)
// ---------------------------------------------------------------------------
__global__ void cvt_feat(const float* __restrict__ x, ushort* __restrict__ xh,
                         unsigned int* __restrict__ xq) {
    int i = blockIdx.x * blockDim.x + threadIdx.x;   // float4 index
    if (i >= (N_NODES * 128) / 4) return;
    f32x4 v = __builtin_nontemporal_load(reinterpret_cast<const f32x4*>(x) + i);
    ushort4 o;
    o.x = f2bf(v.x); o.y = f2bf(v.y); o.z = f2bf(v.z); o.w = f2bf(v.w);
    reinterpret_cast<ushort4*>(xh)[i] = o;
    int p = __builtin_amdgcn_cvt_pk_fp8_f32(v.x, v.y, 0, false);
    p = __builtin_amdgcn_cvt_pk_fp8_f32(v.z, v.w, p, true);
    xq[i] = (unsigned int)p;
}

// Stack [root1; W1_0..W1_4] transposed: Wt[o][seg*128+k] (o: 128 outs).
__global__ void cvt_wstack(const float* __restrict__ W, const float* __restrict__ root,
                           ushort* __restrict__ Wt) {
    int t = blockIdx.x * blockDim.x + threadIdx.x;   // 0..767
    int o = blockIdx.y;
    int seg = t >> 7, k = t & 127;
    float v = (seg == 0) ? root[k * 128 + o] : W[(size_t)(seg - 1) * 128 * 128 + k * 128 + o];
    Wt[(size_t)o * 768 + t] = f2bf(v);
}

// Layer-2 stacked weights: Wt2s[o][k], o 0..95: 0-15 root2, 16+r*16+c = W2_r col c.
__global__ void cvt_w2(const float* __restrict__ W2, const float* __restrict__ root2,
                       ushort* __restrict__ Wt2s) {
    int i = blockIdx.x * blockDim.x + threadIdx.x;
    if (i >= 96 * 128) return;
    int o = i >> 7, k = i & 127;
    float v = (o < 16) ? root2[k * 16 + o]
                       : W2[((size_t)((o >> 4) - 1) * 128 + k) * 16 + (o & 15)];
    Wt2s[i] = f2bf(v);
}

// ---------------------------------------------------------------------------
// Layer-1 gather: one wave per node; fp8 feature table (128 B/edge). Flat
// loop, 8-deep readlane load clusters, scalar boundary flushes.
// A is written ONCE and read ONCE (by gemmL1f) -> NON-TEMPORAL stores so the
// 125 MB write stream doesn't evict the hot 12.8 MB xq table from L3.
// ---------------------------------------------------------------------------
__global__ __launch_bounds__(256) void gather_all(
    const ushort* __restrict__ featq,  // fp8 [N][128] viewed as ushort[N][64]
    const int2* __restrict__ edges,    // (src|rel<<17, w/deg) relation-sorted
    const int* __restrict__ nbase,
    const int2* __restrict__ nbp,
    ushort* __restrict__ A,            // [rows][640] bf16
    int node0) {
    int n = __builtin_amdgcn_readfirstlane(node0 + blockIdx.x * 4 + (threadIdx.x >> 6));
    int lane = threadIdx.x & 63;
    int o0  = __builtin_amdgcn_readfirstlane(nbase[n]);
    int bx  = __builtin_amdgcn_readfirstlane(nbp[n].x);
    int deg = __builtin_amdgcn_readfirstlane(nbp[n].y);
    unsigned int* Ap = reinterpret_cast<unsigned int*>(A) + (size_t)(n - node0) * 320;

    if (deg <= 64) {
        int2 er = (lane < deg) ? edges[o0 + lane] : make_int2(0, 0);
        unsigned long long bp = (unsigned long long)(unsigned)bx
                              | ((unsigned long long)(unsigned)deg << 32);
        float ax = 0.f, ay = 0.f;
        int seg = 0;
        auto flushAt = [&](int jj) {
            while (seg < 5 && jj == (int)((bp >> (seg * 8)) & 0xFFull)) {
                __builtin_nontemporal_store(
                    (unsigned int)f2bf(ax) | ((unsigned int)f2bf(ay) << 16),
                    &Ap[64 * seg + lane]);
                ax = 0.f; ay = 0.f; ++seg;
            }
        };
        int deg8 = (deg + 7) & ~7;
        for (int j = 0; j < deg8; j += 8) {
            // ---- load cluster: 8 independent fp8 gathers in flight ----
            unsigned short q[8];
            float w[8];
            #pragma unroll
            for (int u = 0; u < 8; ++u) {
                int m = __builtin_amdgcn_readlane(er.x, j + u);
                q[u] = featq[((size_t)(m & 0x1FFFF) << 6) + lane];
            }
            #pragma unroll
            for (int u = 0; u < 8; ++u)
                w[u] = __uint_as_float(__builtin_amdgcn_readlane(er.y, j + u));
            // ---- consume, flushing segment snapshots at boundaries ----
            #pragma unroll
            for (int u = 0; u < 8; ++u) {
                flushAt(j + u);
                f32x2 f = __builtin_amdgcn_cvt_pk_f32_fp8((int)q[u], false);
                ax = fmaf(w[u], f.x, ax); ay = fmaf(w[u], f.y, ay);
            }
        }
        while (seg < 5) {
            __builtin_nontemporal_store(
                (unsigned int)f2bf(ax) | ((unsigned int)f2bf(ay) << 16),
                &Ap[64 * seg + lane]);
            ax = 0.f; ay = 0.f; ++seg;
        }
    } else {
        // rare slow path: per-relation sub-ranges
        int B[6];
        B[0] = 0; B[1] = bx & 0xFF; B[2] = (bx >> 8) & 0xFF;
        B[3] = (bx >> 16) & 0xFF; B[4] = (unsigned)bx >> 24; B[5] = deg;
        #pragma unroll
        for (int r = 0; r < 5; ++r) {
            int s0 = o0 + B[r], e1 = o0 + B[r + 1];
            float ax = 0.f, ay = 0.f;
            for (int base = s0; base < e1; base += 64) {
                int2 er = (base + lane < e1) ? edges[base + lane] : make_int2(0, 0);
                int m = e1 - base; if (m > 64) m = 64;
                for (int j = 0; j < m; ++j) {
                    int mm = __builtin_amdgcn_readlane(er.x, j);
                    float w = __uint_as_float(__builtin_amdgcn_readlane(er.y, j));
                    unsigned short qv = featq[((size_t)(mm & 0x1FFFF) << 6) + lane];
                    f32x2 f = __builtin_amdgcn_cvt_pk_f32_fp8((int)qv, false);
                    ax = fmaf(w, f.x, ax);
                    ay = fmaf(w, f.y, ay);
                }
            }
            __builtin_nontemporal_store(
                (unsigned int)f2bf(ax) | ((unsigned int)f2bf(ay) << 16),
                &Ap[r * 64 + lane]);
        }
    }
}

// ---------------------------------------------------------------------------
// FUSED layer-1 GEMM + layer-2 transform:
//   h_blk = relu([xh | A640] @ Wt1^T + b1)   (LDS only — never hits HBM)
//   Yh_blk = h_blk @ Wt2s^T                  (bf16 out)
// A and xh staging loads are NON-TEMPORAL (each row read exactly once).
// ---------------------------------------------------------------------------
__global__ __launch_bounds__(256) void gemmL1f(
    const ushort* __restrict__ xh,   // [N][128] bf16
    const ushort* __restrict__ A,    // chunk-local [rows][640] bf16
    const ushort* __restrict__ Wt,   // [128][768] bf16
    const float* __restrict__ bias,  // [128]
    const ushort* __restrict__ Wt2,  // [96][128] bf16 (L2-resident)
    ushort* __restrict__ Yh,         // [N][96] bf16
    int row0, int nrows) {
    __shared__ ushort lds[128 * 128];        // 32 KB: phase1 As|Bs, then h
    ushort* As = lds;
    ushort* Bs = lds + 128 * 64;
    const int tid = threadIdx.x, lane = tid & 63, wave = tid >> 6;
    const int m0 = blockIdx.x * 128;

    constexpr int MF = 4, NF = 4;
    const int wr0 = (wave >> 1) * 64;
    const int wc0 = (wave & 1) * 64;

    f32x4 acc[MF][NF] = {};

    for (int ks = 0; ks < 12; ++ks) {
        #pragma unroll
        for (int u = 0; u < 4; ++u) {
            int idx = tid + u * 256;
            int row = idx >> 3, slot = idx & 7;
            f32x4 v;
            if (ks < 2) {
                int gr = row0 + m0 + row; if (gr >= N_NODES) gr = N_NODES - 1;
                v = __builtin_nontemporal_load(reinterpret_cast<const f32x4*>(
                    xh + (size_t)gr * 128 + ks * 64 + slot * 8));
            } else {
                v = __builtin_nontemporal_load(reinterpret_cast<const f32x4*>(
                    A + (size_t)(m0 + row) * 640 + (ks - 2) * 64 + slot * 8));
            }
            int byte = row * 128 + ((slot ^ (row & 7)) << 4);
            *reinterpret_cast<f32x4*>(reinterpret_cast<char*>(As) + byte) = v;
        }
        #pragma unroll
        for (int u = 0; u < 4; ++u) {
            int idx = tid + u * 256;
            int row = idx >> 3, slot = idx & 7;
            float4 v = *reinterpret_cast<const float4*>(
                Wt + (size_t)row * 768 + ks * 64 + slot * 8);
            int byte = row * 128 + ((slot ^ (row & 7)) << 4);
            *reinterpret_cast<float4*>(reinterpret_cast<char*>(Bs) + byte) = v;
        }
        __syncthreads();

        #pragma unroll
        for (int kh = 0; kh < 2; ++kh) {
            bf16x8 af[MF], bfr[NF];
            #pragma unroll
            for (int m = 0; m < MF; ++m) {
                int row = wr0 + m * 16 + (lane & 15);
                int slot = kh * 4 + (lane >> 4);
                int byte = row * 128 + ((slot ^ (row & 7)) << 4);
                af[m] = *reinterpret_cast<const bf16x8*>(
                    reinterpret_cast<const char*>(As) + byte);
            }
            #pragma unroll
            for (int nn = 0; nn < NF; ++nn) {
                int row = wc0 + nn * 16 + (lane & 15);
                int slot = kh * 4 + (lane >> 4);
                int byte = row * 128 + ((slot ^ (row & 7)) << 4);
                bfr[nn] = *reinterpret_cast<const bf16x8*>(
                    reinterpret_cast<const char*>(Bs) + byte);
            }
            #pragma unroll
            for (int m = 0; m < MF; ++m)
                #pragma unroll
                for (int nn = 0; nn < NF; ++nn)
                    acc[m][nn] = __builtin_amdgcn_mfma_f32_16x16x32_bf16(
                        af[m], bfr[nn], acc[m][nn], 0, 0, 0);
        }
        __syncthreads();
    }

    // ---- phase-1 epilogue: bias + relu -> h (bf16) into LDS, swizzled ----
    #pragma unroll
    for (int m = 0; m < MF; ++m) {
        int rloc = wr0 + m * 16 + (lane >> 4) * 4;
        #pragma unroll
        for (int nn = 0; nn < NF; ++nn) {
            int c = wc0 + nn * 16 + (lane & 15);
            float bv = bias[c];
            #pragma unroll
            for (int q = 0; q < 4; ++q) {
                int row = rloc + q;
                float v = fmaxf(acc[m][nn][q] + bv, 0.f);
                int byte = row * 256 + ((((c >> 3) ^ (row & 15)) << 4)) + (c & 7) * 2;
                *reinterpret_cast<ushort*>(reinterpret_cast<char*>(lds) + byte) = f2bf(v);
            }
        }
    }
    __syncthreads();

    // ---- phase 2: Yh = h @ Wt2^T (B-frags direct from global L2) ----
    f32x4 acc2[2][6] = {};
    #pragma unroll
    for (int ks = 0; ks < 4; ++ks) {
        bf16x8 af[2], bfr[6];
        #pragma unroll
        for (int m = 0; m < 2; ++m) {
            int row = wave * 32 + m * 16 + (lane & 15);
            int slot = ks * 4 + (lane >> 4);
            int byte = row * 256 + ((slot ^ (row & 15)) << 4);
            af[m] = *reinterpret_cast<const bf16x8*>(
                reinterpret_cast<const char*>(lds) + byte);
        }
        #pragma unroll
        for (int nn = 0; nn < 6; ++nn) {
            int row = nn * 16 + (lane & 15);
            int slot = ks * 4 + (lane >> 4);
            bfr[nn] = *reinterpret_cast<const bf16x8*>(
                Wt2 + (size_t)row * 128 + slot * 8);
        }
        #pragma unroll
        for (int m = 0; m < 2; ++m)
            #pragma unroll
            for (int nn = 0; nn < 6; ++nn)
                acc2[m][nn] = __builtin_amdgcn_mfma_f32_16x16x32_bf16(
                    af[m], bfr[nn], acc2[m][nn], 0, 0, 0);
    }

    #pragma unroll
    for (int m = 0; m < 2; ++m) {
        int rloc = wave * 32 + m * 16 + (lane >> 4) * 4;
        #pragma unroll
        for (int nn = 0; nn < 6; ++nn) {
            int c = nn * 16 + (lane & 15);
            #pragma unroll
            for (int q = 0; q < 4; ++q) {
                int lrow = m0 + rloc + q;
                int grow = row0 + lrow;
                if (lrow < nrows && grow < N_NODES)
                    Yh[(size_t)grow * 96 + c] = f2bf(acc2[m][nn][q]);
            }
        }
    }
}

// ---------------------------------------------------------------------------
// Layer-2 aggregate + bias + log_softmax, fused. 4 nodes/wave, 16 lanes/node.
// ---------------------------------------------------------------------------
__global__ __launch_bounds__(256) void agg2_softmax(
    const ushort* __restrict__ Yh, const int2* __restrict__ edges,
    const int* __restrict__ nbase, const int2* __restrict__ nbp,
    const float* __restrict__ b2, float* __restrict__ out) {
    int wave = threadIdx.x >> 6, lane = threadIdx.x & 63;
    int q = lane >> 4, c = lane & 15;
    int n = (blockIdx.x * 4 + wave) * 4 + q;
    int nn = (n < N_NODES) ? n : N_NODES - 1;
    int o0 = nbase[nn];
    int deg = nbp[nn].y;

    float val = bfu(Yh[(size_t)nn * 96 + c]) + b2[c];

    for (int b = 0; b < deg; b += 16) {
        int2 er = (b + c < deg) ? edges[o0 + b + c] : make_int2(0, 0);
        #pragma unroll
        for (int j = 0; j < 16; ++j) {
            int m = __shfl(er.x, q * 16 + j);
            float w = __uint_as_float(__shfl(er.y, q * 16 + j));
            int s = m & 0x1FFFF;
            int rel = (m >> 17) & 7;
            val = fmaf(w, bfu(Yh[(size_t)s * 96 + 16 + rel * 16 + c]), val);
        }
    }

    // log_softmax over the 16-lane group
    float mx = val;
    #pragma unroll
    for (int i = 1; i < 16; i <<= 1) mx = fmaxf(mx, __shfl_xor(mx, i));
    float ex = expf(val - mx);
    float ssum = ex;
    #pragma unroll
    for (int i = 1; i < 16; i <<= 1) ssum += __shfl_xor(ssum, i);
    float r = val - mx - logf(ssum);
    if (n < N_NODES) out[(size_t)n * 16 + c] = r;
}

// ---------------------------------------------------------------------------
extern "C" void kernel_launch(void* const* d_in, const int* in_sizes, int n_in,
                              void* d_out, int out_size, void* d_ws, size_t ws_size,
                              hipStream_t stream) {
    const float* x     = (const float*)d_in[0];
    const int*   ei    = (const int*)d_in[1];
    const int*   src   = ei;
    const int*   dst   = ei + N_EDGES;
    const float* ew    = (const float*)d_in[2];
    const int*   et    = (const int*)d_in[3];
    const float* W1    = (const float*)d_in[4];
    const float* root1 = (const float*)d_in[5];
    const float* b1    = (const float*)d_in[6];
    const float* W2    = (const float*)d_in[7];
    const float* root2 = (const float*)d_in[8];
    const float* b2    = (const float*)d_in[9];
    float* out = (float*)d_out;

    // workspace layout
    char* ws = (char*)d_ws;
    int*    ccur    = (int*)ws;                        //      1,024 B
    int*    cstart  = (int*)(ws + 1024);               //      1,024 B
    int*    nbase   = (int*)(ws + 4096);               //    400,000 B
    int2*   nbp     = (int2*)(ws + 404096);            //    800,000 B
    int2*   edges   = (int2*)(ws + 1204096);           // 12,800,000 B
    ushort* xh      = (ushort*)(ws + 18018304);        // 25,600,000 B
    ushort* Wt1     = (ushort*)(ws + 43618304);        //    196,608 B
    ushort* Wt2s    = (ushort*)(ws + 43814912);        //     24,576 B
    unsigned int* xq = (unsigned int*)(ws + 43839488); // 12,800,000 B (fp8 table)
    // union region @56,639,488: pe (25.7MB, build only) -> Abuf
    int2*   pe      = (int2*)(ws + 56639488);
    ushort* Abuf    = (ushort*)(ws + 56639488);

    // chunking: full-size A = 100096*1280 B = 128.1 MB
    const int chunk = (ws_size >= 225000000ull) ? N_NODES : 25000;
    const int nch   = N_NODES / chunk;
    // Yh after the A region (full) or after the 32MB chunk A (chunked)
    ushort* Yh = (ushort*)(ws + 56639488 +
        (chunk == N_NODES ? 128122880ull : 32112640ull));

    // --- precision conversions (x read once -> bf16 + fp8 tables) ---
    cvt_feat<<<((N_NODES * 128 / 4) + 255) / 256, 256, 0, stream>>>(x, xh, xq);
    cvt_wstack<<<dim3(3, 128), 256, 0, stream>>>(W1, root1, Wt1);
    cvt_w2<<<(96 * 128 + 255) / 256, 256, 0, stream>>>(W2, root2, Wt2s);

    // --- build (dst,rel)-bucketed CSR: 3 passes ---
    hipMemsetAsync(ccur, 0, 1024, stream);
    partition_append<<<(N_EDGES + 4095) / 4096, 1024, 0, stream>>>(src, dst, ew, et, ccur, pe);
    cscan<<<1, 256, 0, stream>>>(ccur, cstart);
    bucket_sort<<<NCOARSE, 1024, 0, stream>>>(ccur, cstart, pe, edges, nbase, nbp);

    // --- layer 1 + layer-2 transform, fused (h never hits HBM) ---
    for (int cc = 0; cc < nch; ++cc) {
        gather_all<<<chunk / 4, 256, 0, stream>>>(
            (const ushort*)xq, edges, nbase, nbp, Abuf, cc * chunk);
        gemmL1f<<<(chunk + 127) / 128, 256, 0, stream>>>(
            xh, Abuf, Wt1, b1, Wt2s, Yh, cc * chunk, chunk);
    }

    // --- layer-2 aggregate + bias + log_softmax ---
    agg2_softmax<<<(N_NODES + 15) / 16, 256, 0, stream>>>(
        Yh, edges, nbase, nbp, b2, out);
}

// Round 15
// 205.808 us; speedup vs baseline: 1.0886x; 1.0886x over previous
//
#include <hip/hip_runtime.h>

// Problem constants (from reference)
#define N_NODES 100000
#define N_EDGES 1600000
#define N_REL   5
#define NCOARSE  196                         // ceil(N_NODES / 512) coarse buckets
#define CAP      16384                       // pe capacity per coarse bucket (avg 8163)

using bf16x8 = __attribute__((ext_vector_type(8))) short;
using f32x4  = __attribute__((ext_vector_type(4))) float;
using f32x2  = __attribute__((ext_vector_type(2))) float;

__device__ __forceinline__ unsigned short f2bf(float f) {
    unsigned int u = __float_as_uint(f);
    u += 0x7fffu + ((u >> 16) & 1u);          // RNE
    return (unsigned short)(u >> 16);
}
__device__ __forceinline__ float bfu(unsigned short u) { return __uint_as_float((unsigned int)u << 16); }

// ---------------------------------------------------------------------------
// Pass 1: append edges into coarse (dst>>9) regions of pe.
// Record = (src | rel<<17 | dlow9<<20, ew).
// ---------------------------------------------------------------------------
__global__ __launch_bounds__(1024) void partition_append(
    const int* __restrict__ src, const int* __restrict__ dstv,
    const float* __restrict__ ew, const int* __restrict__ et,
    int* __restrict__ ccur, int2* __restrict__ pe) {
    __shared__ int lh[256];
    __shared__ int lb[256];
    int tid = threadIdx.x;
    if (tid < 256) lh[tid] = 0;
    __syncthreads();
    int base = blockIdx.x * 4096;
    int key[4], rank[4], meta[4];
    float w[4];
    #pragma unroll
    for (int i = 0; i < 4; ++i) {
        int e = base + i * 1024 + tid;
        key[i] = -1;
        if (e < N_EDGES) {
            int d = dstv[e];
            key[i] = d >> 9;
            meta[i] = src[e] | (et[e] << 17) | ((d & 511) << 20);
            w[i] = ew[e];
            rank[i] = atomicAdd(&lh[key[i]], 1);
        }
    }
    __syncthreads();
    if (tid < 256) {
        int c = lh[tid];
        lb[tid] = c ? atomicAdd(&ccur[tid], c) : 0;
    }
    __syncthreads();
    #pragma unroll
    for (int i = 0; i < 4; ++i)
        if (key[i] >= 0) {
            int pos = lb[key[i]] + rank[i];
            if (pos < CAP)
                pe[((size_t)key[i] << 14) + pos] = make_int2(meta[i], __float_as_int(w[i]));
        }
}

// Pass 2 (tiny): exclusive scan of 256 coarse counts -> global bases.
__global__ __launch_bounds__(256) void cscan(const int* __restrict__ ccur,
                                             int* __restrict__ cstart) {
    __shared__ int lds[256];
    int tid = threadIdx.x;
    int v = ccur[tid];
    lds[tid] = v;
    __syncthreads();
    for (int d = 1; d < 256; d <<= 1) {
        int t = (tid >= d) ? lds[tid - d] : 0;
        __syncthreads();
        lds[tid] += t;
        __syncthreads();
    }
    cstart[tid] = lds[tid] - v;
}

// ---------------------------------------------------------------------------
// Pass 3: one block per coarse bucket. Fine histogram, wave-shfl scan,
// per-node descriptors (nbase + degree), dense scatter (relation-sorted
// within node). 1/deg folded into w; rel kept in bits 17-19.
// ---------------------------------------------------------------------------
__global__ __launch_bounds__(1024) void bucket_sort(
    const int* __restrict__ ccnt, const int* __restrict__ cstart,
    const int2* __restrict__ pe, int2* __restrict__ edges,
    int* __restrict__ nbase, int2* __restrict__ nbp) {
    int cb = blockIdx.x;
    int node0 = cb << 9;
    if (node0 >= N_NODES) return;
    int nNodes = N_NODES - node0; if (nNodes > 512) nNodes = 512;
    int nf = nNodes * N_REL;
    __shared__ int hist[2560];
    __shared__ int cur[2560];
    __shared__ int wtot[16];
    __shared__ int woff[16];
    int tid = threadIdx.x;
    int wid = tid >> 6, lane = tid & 63;
    int cnt = ccnt[cb]; if (cnt > CAP) cnt = CAP;
    int gbase = cstart[cb];
    const int2* my = pe + ((size_t)cb << 14);

    for (int i = tid; i < nf; i += 1024) hist[i] = 0;
    __syncthreads();
    for (int i = tid; i < cnt; i += 1024) {
        int m = my[i].x;
        atomicAdd(&hist[((m >> 20) & 511) * N_REL + ((m >> 17) & 7)], 1);
    }
    __syncthreads();

    // exclusive scan over hist: 3 elems/thread, wave shfl-scan + 16 partials
    int t0 = tid * 3;
    int a0 = (t0 + 0 < nf) ? hist[t0 + 0] : 0;
    int a1 = (t0 + 1 < nf) ? hist[t0 + 1] : 0;
    int a2 = (t0 + 2 < nf) ? hist[t0 + 2] : 0;
    int s = a0 + a1 + a2;
    int incl = s;
    #pragma unroll
    for (int d = 1; d < 64; d <<= 1) {
        int t = __shfl_up(incl, d);
        if (lane >= d) incl += t;
    }
    if (lane == 63) wtot[wid] = incl;
    __syncthreads();
    if (wid == 0 && lane < 16) {
        int v = wtot[lane];
        int inc2 = v;
        #pragma unroll
        for (int d = 1; d < 16; d <<= 1) {
            int t = __shfl_up(inc2, d);
            if (lane >= d) inc2 += t;
        }
        woff[lane] = inc2 - v;
    }
    __syncthreads();
    int excl = incl - s + woff[wid];
    if (t0 + 0 < nf) cur[t0 + 0] = excl;
    excl += a0;
    if (t0 + 1 < nf) cur[t0 + 1] = excl;
    excl += a1;
    if (t0 + 2 < nf) cur[t0 + 2] = excl;
    __syncthreads();

    // per-node descriptors: base + degree (boundaries unused now but cheap)
    for (int i = tid; i < nNodes; i += 1024) {
        int b = i * N_REL;
        int c0 = cur[b];
        int deg = cur[b + 4] + hist[b + 4] - c0;
        nbase[node0 + i] = gbase + c0;
        nbp[node0 + i] = make_int2(0, deg);
    }
    __syncthreads();

    for (int i = tid; i < cnt; i += 1024) {
        int2 r = my[i];
        int fb = ((r.x >> 20) & 511) * N_REL + ((r.x >> 17) & 7);
        int pos = gbase + atomicAdd(&cur[fb], 1);
        float wf = __int_as_float(r.y) / (float)hist[fb];   // fold 1/deg
        edges[pos] = make_int2(r.x & 0xFFFFF, __float_as_int(wf)); // src|rel<<17
    }
}

// ---------------------------------------------------------------------------
// Feature conversion: x -> xh (bf16)
// ---------------------------------------------------------------------------
__global__ void cvt_feat(const float* __restrict__ x, ushort* __restrict__ xh) {
    int i = blockIdx.x * blockDim.x + threadIdx.x;   // float4 index
    if (i >= (N_NODES * 128) / 4) return;
    float4 v = reinterpret_cast<const float4*>(x)[i];
    ushort4 o;
    o.x = f2bf(v.x); o.y = f2bf(v.y); o.z = f2bf(v.z); o.w = f2bf(v.w);
    reinterpret_cast<ushort4*>(xh)[i] = o;
}

// W1 [5][128][128] -> Wt1b bf16 [640][128]: Wt1b[r*128+o][k] = W1[r][k][o]
__global__ void cvt_w1b(const float* __restrict__ W1, ushort* __restrict__ Wt1b) {
    int i = blockIdx.x * blockDim.x + threadIdx.x;
    if (i >= 640 * 128) return;
    int o640 = i >> 7, k = i & 127;
    int r = o640 >> 7, o = o640 & 127;
    Wt1b[i] = f2bf(W1[((size_t)r * 128 + k) * 128 + o]);
}

// root1 [128][128] -> Wtroot bf16 [o][k]
__global__ void cvt_root(const float* __restrict__ root1, ushort* __restrict__ Wtroot) {
    int i = blockIdx.x * blockDim.x + threadIdx.x;
    if (i >= 128 * 128) return;
    int o = i >> 7, k = i & 127;
    Wtroot[i] = f2bf(root1[k * 128 + o]);
}

// Layer-2 stacked weights: Wt2s[o][k], o 0..95: 0-15 root2, 16+r*16+c = W2_r col c.
__global__ void cvt_w2(const float* __restrict__ W2, const float* __restrict__ root2,
                       ushort* __restrict__ Wt2s) {
    int i = blockIdx.x * blockDim.x + threadIdx.x;
    if (i >= 96 * 128) return;
    int o = i >> 7, k = i & 127;
    float v = (o < 16) ? root2[k * 16 + o]
                       : W2[((size_t)((o >> 4) - 1) * 128 + k) * 16 + (o & 15)];
    Wt2s[i] = f2bf(v);
}

// ---------------------------------------------------------------------------
// gemmZ: Z[n][640] = fp8(xh[n][128] @ Wt1b[640][128]^T)
// Block = 128 rows; As = xh tile (32 KB); per output segment (5 x 128 cols):
// stage Bs (32 KB), 4 K-steps, fp8-pack epilogue (byte stores).
// ---------------------------------------------------------------------------
__global__ __launch_bounds__(256) void gemmZ(
    const ushort* __restrict__ xh, const ushort* __restrict__ Wt1b,
    unsigned char* __restrict__ Zq) {
    __shared__ ushort As[128 * 128];   // 32 KB
    __shared__ ushort Bs[128 * 128];   // 32 KB
    const int tid = threadIdx.x, lane = tid & 63, wave = tid >> 6;
    const int m0 = blockIdx.x * 128;

    #pragma unroll
    for (int u = 0; u < 8; ++u) {
        int idx = tid + u * 256;
        int row = idx >> 4, slot = idx & 15;
        int gr = m0 + row; if (gr >= N_NODES) gr = N_NODES - 1;
        float4 v = *reinterpret_cast<const float4*>(xh + (size_t)gr * 128 + slot * 8);
        int byte = row * 256 + ((slot ^ (row & 15)) << 4);
        *reinterpret_cast<float4*>(reinterpret_cast<char*>(As) + byte) = v;
    }

    for (int seg = 0; seg < 5; ++seg) {
        #pragma unroll
        for (int u = 0; u < 8; ++u) {
            int idx = tid + u * 256;
            int row = idx >> 4, slot = idx & 15;
            float4 v = *reinterpret_cast<const float4*>(
                Wt1b + ((size_t)(seg * 128 + row)) * 128 + slot * 8);
            int byte = row * 256 + ((slot ^ (row & 15)) << 4);
            *reinterpret_cast<float4*>(reinterpret_cast<char*>(Bs) + byte) = v;
        }
        __syncthreads();

        f32x4 acc[2][8] = {};
        #pragma unroll
        for (int ks = 0; ks < 4; ++ks) {
            bf16x8 af[2], bfr[8];
            #pragma unroll
            for (int m = 0; m < 2; ++m) {
                int row = wave * 32 + m * 16 + (lane & 15);
                int slot = ks * 4 + (lane >> 4);
                int byte = row * 256 + ((slot ^ (row & 15)) << 4);
                af[m] = *reinterpret_cast<const bf16x8*>(
                    reinterpret_cast<const char*>(As) + byte);
            }
            #pragma unroll
            for (int nn = 0; nn < 8; ++nn) {
                int row = nn * 16 + (lane & 15);
                int slot = ks * 4 + (lane >> 4);
                int byte = row * 256 + ((slot ^ (row & 15)) << 4);
                bfr[nn] = *reinterpret_cast<const bf16x8*>(
                    reinterpret_cast<const char*>(Bs) + byte);
            }
            #pragma unroll
            for (int m = 0; m < 2; ++m)
                #pragma unroll
                for (int nn = 0; nn < 8; ++nn)
                    acc[m][nn] = __builtin_amdgcn_mfma_f32_16x16x32_bf16(
                        af[m], bfr[nn], acc[m][nn], 0, 0, 0);
        }

        #pragma unroll
        for (int m = 0; m < 2; ++m) {
            int rloc = m0 + wave * 32 + m * 16 + (lane >> 4) * 4;
            #pragma unroll
            for (int nn = 0; nn < 8; ++nn) {
                int c = seg * 128 + nn * 16 + (lane & 15);
                #pragma unroll
                for (int q = 0; q < 4; ++q) {
                    int row = rloc + q;
                    if (row < N_NODES) {
                        float v = acc[m][nn][q];
                        int p = __builtin_amdgcn_cvt_pk_fp8_f32(v, v, 0, false);
                        Zq[(size_t)row * 640 + c] = (unsigned char)(p & 0xFF);
                    }
                }
            }
        }
        __syncthreads();   // before next seg overwrites Bs
    }
}

// ---------------------------------------------------------------------------
// gather2: output-space aggregation. One wave per node, single accumulator
// (all relations collapse: addr = (src*5+rel)*128 fp8, w has 1/deg folded).
// No segment flushes. 8-deep load clusters; scalar address math (readlane ->
// SGPR). Writes hpre bf16 [N][128].
// ---------------------------------------------------------------------------
__global__ __launch_bounds__(256) void gather2(
    const ushort* __restrict__ Zq,     // fp8 [N][640] viewed as ushort
    const int2* __restrict__ edges,    // (src|rel<<17, w/deg) sorted per node
    const int* __restrict__ nbase, const int2* __restrict__ nbp,
    ushort* __restrict__ hpre) {       // bf16 [N][128]
    int n = __builtin_amdgcn_readfirstlane(blockIdx.x * 4 + (threadIdx.x >> 6));
    int lane = threadIdx.x & 63;
    int o0  = __builtin_amdgcn_readfirstlane(nbase[n]);
    int deg = __builtin_amdgcn_readfirstlane(nbp[n].y);
    float ax = 0.f, ay = 0.f;

    if (deg <= 64) {
        int2 er = (lane < deg) ? edges[o0 + lane] : make_int2(0, 0);
        int deg8 = (deg + 7) & ~7;
        for (int j = 0; j < deg8; j += 8) {
            unsigned short q[8];
            float w[8];
            #pragma unroll
            for (int u = 0; u < 8; ++u) {
                int m = __builtin_amdgcn_readlane(er.x, j + u);
                int s5 = (m & 0x1FFFF) * 5 + ((m >> 17) & 7);
                q[u] = Zq[((size_t)s5 << 6) + lane];
            }
            #pragma unroll
            for (int u = 0; u < 8; ++u)
                w[u] = __uint_as_float(__builtin_amdgcn_readlane(er.y, j + u));
            #pragma unroll
            for (int u = 0; u < 8; ++u) {
                f32x2 f = __builtin_amdgcn_cvt_pk_f32_fp8((int)q[u], false);
                ax = fmaf(w[u], f.x, ax); ay = fmaf(w[u], f.y, ay);
            }
        }
    } else {
        for (int base = o0; base < o0 + deg; base += 64) {
            int rem = o0 + deg - base;
            int mcap = rem > 64 ? 64 : rem;
            int2 er = (lane < mcap) ? edges[base + lane] : make_int2(0, 0);
            int m8 = (mcap + 7) & ~7;
            for (int j = 0; j < m8; j += 8) {
                unsigned short q[8];
                float w[8];
                #pragma unroll
                for (int u = 0; u < 8; ++u) {
                    int m = __builtin_amdgcn_readlane(er.x, j + u);
                    int s5 = (m & 0x1FFFF) * 5 + ((m >> 17) & 7);
                    q[u] = Zq[((size_t)s5 << 6) + lane];
                }
                #pragma unroll
                for (int u = 0; u < 8; ++u)
                    w[u] = __uint_as_float(__builtin_amdgcn_readlane(er.y, j + u));
                #pragma unroll
                for (int u = 0; u < 8; ++u) {
                    f32x2 f = __builtin_amdgcn_cvt_pk_f32_fp8((int)q[u], false);
                    ax = fmaf(w[u], f.x, ax); ay = fmaf(w[u], f.y, ay);
                }
            }
        }
    }

    reinterpret_cast<unsigned int*>(hpre)[(size_t)n * 64 + lane] =
        (unsigned int)f2bf(ax) | ((unsigned int)f2bf(ay) << 16);
}

// ---------------------------------------------------------------------------
// gemmL1fr: h = relu(xh @ Wtroot^T + hpre + b1)  (h stays in LDS),
// then Yh = h @ Wt2s^T.  Block = 128 rows, 64 KB LDS (As reused for h).
// ---------------------------------------------------------------------------
__global__ __launch_bounds__(256) void gemmL1fr(
    const ushort* __restrict__ xh,     // [N][128] bf16
    const ushort* __restrict__ Wtroot, // [128][128] bf16
    const float* __restrict__ bias,    // [128]
    const ushort* __restrict__ hpre,   // [N][128] bf16
    const ushort* __restrict__ Wt2,    // [96][128] bf16 (L2-resident)
    ushort* __restrict__ Yh) {         // [N][96] bf16
    __shared__ ushort As[128 * 128];   // 32 KB; reused for h after phase 1
    __shared__ ushort Bs[128 * 128];   // 32 KB
    const int tid = threadIdx.x, lane = tid & 63, wave = tid >> 6;
    const int m0 = blockIdx.x * 128;

    #pragma unroll
    for (int u = 0; u < 8; ++u) {
        int idx = tid + u * 256;
        int row = idx >> 4, slot = idx & 15;
        int gr = m0 + row; if (gr >= N_NODES) gr = N_NODES - 1;
        float4 v = *reinterpret_cast<const float4*>(xh + (size_t)gr * 128 + slot * 8);
        int byte = row * 256 + ((slot ^ (row & 15)) << 4);
        *reinterpret_cast<float4*>(reinterpret_cast<char*>(As) + byte) = v;
    }
    #pragma unroll
    for (int u = 0; u < 8; ++u) {
        int idx = tid + u * 256;
        int row = idx >> 4, slot = idx & 15;
        float4 v = *reinterpret_cast<const float4*>(Wtroot + (size_t)row * 128 + slot * 8);
        int byte = row * 256 + ((slot ^ (row & 15)) << 4);
        *reinterpret_cast<float4*>(reinterpret_cast<char*>(Bs) + byte) = v;
    }
    __syncthreads();

    // phase 1: xh @ root^T  (K=128)
    f32x4 acc[2][8] = {};
    #pragma unroll
    for (int ks = 0; ks < 4; ++ks) {
        bf16x8 af[2], bfr[8];
        #pragma unroll
        for (int m = 0; m < 2; ++m) {
            int row = wave * 32 + m * 16 + (lane & 15);
            int slot = ks * 4 + (lane >> 4);
            int byte = row * 256 + ((slot ^ (row & 15)) << 4);
            af[m] = *reinterpret_cast<const bf16x8*>(
                reinterpret_cast<const char*>(As) + byte);
        }
        #pragma unroll
        for (int nn = 0; nn < 8; ++nn) {
            int row = nn * 16 + (lane & 15);
            int slot = ks * 4 + (lane >> 4);
            int byte = row * 256 + ((slot ^ (row & 15)) << 4);
            bfr[nn] = *reinterpret_cast<const bf16x8*>(
                reinterpret_cast<const char*>(Bs) + byte);
        }
        #pragma unroll
        for (int m = 0; m < 2; ++m)
            #pragma unroll
            for (int nn = 0; nn < 8; ++nn)
                acc[m][nn] = __builtin_amdgcn_mfma_f32_16x16x32_bf16(
                    af[m], bfr[nn], acc[m][nn], 0, 0, 0);
    }
    __syncthreads();   // all As/Bs reads done before h overwrites As

    // epilogue: h = relu(acc + bias + hpre) -> LDS (phase-2 layout)
    #pragma unroll
    for (int m = 0; m < 2; ++m) {
        int rloc = wave * 32 + m * 16 + (lane >> 4) * 4;
        #pragma unroll
        for (int nn = 0; nn < 8; ++nn) {
            int c = nn * 16 + (lane & 15);
            float bv = bias[c];
            #pragma unroll
            for (int q = 0; q < 4; ++q) {
                int row = rloc + q;
                int grow = m0 + row; if (grow >= N_NODES) grow = N_NODES - 1;
                float v = fmaxf(acc[m][nn][q] + bv +
                                bfu(hpre[(size_t)grow * 128 + c]), 0.f);
                int byte = row * 256 + ((((c >> 3) ^ (row & 15)) << 4)) + (c & 7) * 2;
                *reinterpret_cast<ushort*>(reinterpret_cast<char*>(As) + byte) = f2bf(v);
            }
        }
    }
    __syncthreads();

    // phase 2: Yh = h @ Wt2^T (B-frags direct from global L2)
    f32x4 acc2[2][6] = {};
    #pragma unroll
    for (int ks = 0; ks < 4; ++ks) {
        bf16x8 af[2], bfr[6];
        #pragma unroll
        for (int m = 0; m < 2; ++m) {
            int row = wave * 32 + m * 16 + (lane & 15);
            int slot = ks * 4 + (lane >> 4);
            int byte = row * 256 + ((slot ^ (row & 15)) << 4);
            af[m] = *reinterpret_cast<const bf16x8*>(
                reinterpret_cast<const char*>(As) + byte);
        }
        #pragma unroll
        for (int nn = 0; nn < 6; ++nn) {
            int row = nn * 16 + (lane & 15);
            int slot = ks * 4 + (lane >> 4);
            bfr[nn] = *reinterpret_cast<const bf16x8*>(
                Wt2 + (size_t)row * 128 + slot * 8);
        }
        #pragma unroll
        for (int m = 0; m < 2; ++m)
            #pragma unroll
            for (int nn = 0; nn < 6; ++nn)
                acc2[m][nn] = __builtin_amdgcn_mfma_f32_16x16x32_bf16(
                    af[m], bfr[nn], acc2[m][nn], 0, 0, 0);
    }

    #pragma unroll
    for (int m = 0; m < 2; ++m) {
        int rloc = wave * 32 + m * 16 + (lane >> 4) * 4;
        #pragma unroll
        for (int nn = 0; nn < 6; ++nn) {
            int c = nn * 16 + (lane & 15);
            #pragma unroll
            for (int q = 0; q < 4; ++q) {
                int grow = m0 + rloc + q;
                if (grow < N_NODES)
                    Yh[(size_t)grow * 96 + c] = f2bf(acc2[m][nn][q]);
            }
        }
    }
}

// ---------------------------------------------------------------------------
// Layer-2 aggregate + bias + log_softmax, fused. 4 nodes/wave, 16 lanes/node.
// ---------------------------------------------------------------------------
__global__ __launch_bounds__(256) void agg2_softmax(
    const ushort* __restrict__ Yh, const int2* __restrict__ edges,
    const int* __restrict__ nbase, const int2* __restrict__ nbp,
    const float* __restrict__ b2, float* __restrict__ out) {
    int wave = threadIdx.x >> 6, lane = threadIdx.x & 63;
    int q = lane >> 4, c = lane & 15;
    int n = (blockIdx.x * 4 + wave) * 4 + q;
    int nn = (n < N_NODES) ? n : N_NODES - 1;
    int o0 = nbase[nn];
    int deg = nbp[nn].y;

    float val = bfu(Yh[(size_t)nn * 96 + c]) + b2[c];

    for (int b = 0; b < deg; b += 16) {
        int2 er = (b + c < deg) ? edges[o0 + b + c] : make_int2(0, 0);
        #pragma unroll
        for (int j = 0; j < 16; ++j) {
            int m = __shfl(er.x, q * 16 + j);
            float w = __uint_as_float(__shfl(er.y, q * 16 + j));
            int s = m & 0x1FFFF;
            int rel = (m >> 17) & 7;
            val = fmaf(w, bfu(Yh[(size_t)s * 96 + 16 + rel * 16 + c]), val);
        }
    }

    // log_softmax over the 16-lane group
    float mx = val;
    #pragma unroll
    for (int i = 1; i < 16; i <<= 1) mx = fmaxf(mx, __shfl_xor(mx, i));
    float ex = expf(val - mx);
    float ssum = ex;
    #pragma unroll
    for (int i = 1; i < 16; i <<= 1) ssum += __shfl_xor(ssum, i);
    float r = val - mx - logf(ssum);
    if (n < N_NODES) out[(size_t)n * 16 + c] = r;
}

// ---------------------------------------------------------------------------
extern "C" void kernel_launch(void* const* d_in, const int* in_sizes, int n_in,
                              void* d_out, int out_size, void* d_ws, size_t ws_size,
                              hipStream_t stream) {
    const float* x     = (const float*)d_in[0];
    const int*   ei    = (const int*)d_in[1];
    const int*   src   = ei;
    const int*   dst   = ei + N_EDGES;
    const float* ew    = (const float*)d_in[2];
    const int*   et    = (const int*)d_in[3];
    const float* W1    = (const float*)d_in[4];
    const float* root1 = (const float*)d_in[5];
    const float* b1    = (const float*)d_in[6];
    const float* W2    = (const float*)d_in[7];
    const float* root2 = (const float*)d_in[8];
    const float* b2    = (const float*)d_in[9];
    float* out = (float*)d_out;

    // workspace layout (~174 MB, all disjoint)
    char* ws = (char*)d_ws;
    int*    ccur    = (int*)ws;                        //      1,024 B
    int*    cstart  = (int*)(ws + 1024);               //      1,024 B
    int*    nbase   = (int*)(ws + 4096);               //    400,000 B
    int2*   nbp     = (int2*)(ws + 404096);            //    800,000 B
    int2*   edges   = (int2*)(ws + 1204096);           // 12,800,000 B
    ushort* xh      = (ushort*)(ws + 14004096);        // 25,600,000 B
    ushort* Wt1b    = (ushort*)(ws + 39604096);        //    163,840 B
    ushort* Wtroot  = (ushort*)(ws + 39767936);        //     32,768 B
    ushort* Wt2s    = (ushort*)(ws + 39800704);        //     24,576 B
    ushort* hpre    = (ushort*)(ws + 39825280);        // 25,600,000 B
    unsigned char* Zq = (unsigned char*)(ws + 65425280); // 64,000,000 B
    ushort* Yh      = (ushort*)(ws + 129425280);       // 19,200,000 B
    int2*   pe      = (int2*)(ws + 148625280);         // 25,690,112 B

    // --- conversions ---
    cvt_feat<<<((N_NODES * 128 / 4) + 255) / 256, 256, 0, stream>>>(x, xh);
    cvt_w1b<<<(640 * 128 + 255) / 256, 256, 0, stream>>>(W1, Wt1b);
    cvt_root<<<(128 * 128 + 255) / 256, 256, 0, stream>>>(root1, Wtroot);
    cvt_w2<<<(96 * 128 + 255) / 256, 256, 0, stream>>>(W2, root2, Wt2s);

    // --- build (dst,rel)-bucketed CSR: 3 passes ---
    hipMemsetAsync(ccur, 0, 1024, stream);
    partition_append<<<(N_EDGES + 4095) / 4096, 1024, 0, stream>>>(src, dst, ew, et, ccur, pe);
    cscan<<<1, 256, 0, stream>>>(ccur, cstart);
    bucket_sort<<<NCOARSE, 1024, 0, stream>>>(ccur, cstart, pe, edges, nbase, nbp);

    // --- layer 1, transform-first: Z = fp8(xh @ W1stack^T) ---
    gemmZ<<<(N_NODES + 127) / 128, 256, 0, stream>>>(xh, Wt1b, Zq);

    // --- output-space aggregation: hpre = sum_e w'_e * Z[src_e, rel_e] ---
    gather2<<<N_NODES / 4, 256, 0, stream>>>(
        (const ushort*)Zq, edges, nbase, nbp, hpre);

    // --- h = relu(xh@root1 + hpre + b1); Yh = h @ Wt2s^T (fused) ---
    gemmL1fr<<<(N_NODES + 127) / 128, 256, 0, stream>>>(
        xh, Wtroot, b1, hpre, Wt2s, Yh);

    // --- layer-2 aggregate + bias + log_softmax ---
    agg2_softmax<<<(N_NODES + 15) / 16, 256, 0, stream>>>(
        Yh, edges, nbase, nbp, b2, out);
}